// Round 14
// baseline (169.875 us; speedup 1.0000x reference)
//
#include <hip/hip_runtime.h>
#include <hip/hip_bf16.h>
#include <stdint.h>

typedef __attribute__((ext_vector_type(8))) short bf16x8;
typedef __attribute__((ext_vector_type(8))) unsigned short ushort8;
typedef __attribute__((ext_vector_type(4))) float f32x4;
typedef __attribute__((ext_vector_type(16))) float f32x16;
typedef __attribute__((ext_vector_type(4))) unsigned int u32x4;

#define MFMA16(a, b, c) __builtin_amdgcn_mfma_f32_16x16x32_bf16((a), (b), (c), 0, 0, 0)
#define MFMA32(a, b, c) __builtin_amdgcn_mfma_f32_32x32x16_bf16((a), (b), (c), 0, 0, 0)

__device__ __forceinline__ unsigned short f2bf(float f) {
  unsigned int u = __builtin_bit_cast(unsigned int, f);
  unsigned int r = (u + 0x7fffu + ((u >> 16) & 1u)) >> 16;
  return (unsigned short)r;
}

__device__ __forceinline__ void gload16(const unsigned short* g, unsigned short* lds_dst) {
  __builtin_amdgcn_global_load_lds(
      (const __attribute__((address_space(1))) unsigned int*)g,
      (__attribute__((address_space(3))) unsigned int*)lds_dst, 16, 0, 0);
}

// ---------------- fused f32 -> bf16 conversion (single launch) ----------------
__global__ void cvt_all(const float* __restrict__ x, const float* __restrict__ wa,
                        const float* __restrict__ wp, unsigned short* __restrict__ xb,
                        unsigned short* __restrict__ wab, unsigned short* __restrict__ wpb) {
  const int C0 = 1048576;
  const int C1 = 1441792;
  const int C2 = 1572864;
  int i = blockIdx.x * blockDim.x + threadIdx.x;
  const int stride = gridDim.x * blockDim.x;
  for (; i < C2; i += stride) {
    const float* src; unsigned short* dst; long e;
    if (i < C0)      { src = x;  dst = xb;  e = (long)i * 8; }
    else if (i < C1) { src = wa; dst = wab; e = (long)(i - C0) * 8; }
    else             { src = wp; dst = wpb; e = (long)(i - C1) * 8; }
    float4 v0 = *(const float4*)(src + e);
    float4 v1 = *(const float4*)(src + e + 4);
    ushort8 o;
    o[0] = f2bf(v0.x); o[1] = f2bf(v0.y); o[2] = f2bf(v0.z); o[3] = f2bf(v0.w);
    o[4] = f2bf(v1.x); o[5] = f2bf(v1.y); o[6] = f2bf(v1.z); o[7] = f2bf(v1.w);
    *(ushort8*)(dst + e) = o;
  }
}

// ------- 256 x (NB*64) B^T GEMM: r6 schedule + LDS-transpose epilogue -------
// (unchanged from r13 — best measured)
template <int EPI, int NB>
__global__ __launch_bounds__(512, 2)
void gemm_bt(const unsigned short* __restrict__ A,
             const unsigned short* __restrict__ Bt,
             const float* __restrict__ bias,
             int M, int N, int K,
             unsigned short* __restrict__ q_out,
             unsigned short* __restrict__ k_out,
             unsigned short* __restrict__ vt_out,
             float* __restrict__ f_out) {
  constexpr int BNT = NB * 64;
  alignas(16) __shared__ unsigned short Alds[2][2][128 * 64];
  alignas(16) __shared__ unsigned short Blds[2][BNT * 64];
  const int t = threadIdx.x, w = t >> 6, l = t & 63;
  const int bm = blockIdx.x, bn = blockIdx.y;
  const int wm = w >> 2, wn = w & 3;
  const int lo = l & 15, hi = l >> 4, swk = lo & 7;

  f32x4 acc[8][NB];
  const f32x4 zero = {0.f, 0.f, 0.f, 0.f};
#pragma unroll
  for (int i = 0; i < 8; ++i)
#pragma unroll
    for (int j = 0; j < NB; ++j) acc[i][j] = zero;

  const int sr = t >> 3;
  const int gsrcE = ((t & 7) ^ (sr & 7)) * 8;
  const unsigned short* Asrc = A + (long)(bm * 256 + sr) * K + gsrcE;
  const unsigned short* Bsrc = Bt + (long)(bn * BNT + sr) * K + gsrcE;

#define STAGE_AH(sb, qh, koff) do {                                    \
    unsigned short* d_ = &Alds[sb][qh][w * 512];                       \
    const unsigned short* s_ = Asrc + (long)(qh) * 64 * K + (koff);    \
    gload16(s_, d_); gload16(s_ + 128L * K, d_ + 4096); } while (0)
#define STAGE_B(sb, koff) do {                                         \
    _Pragma("unroll")                                                  \
    for (int c_ = 0; c_ < NB; ++c_)                                    \
      gload16(Bsrc + (long)c_ * 64 * K + (koff),                       \
              &Blds[sb][c_ * 4096 + w * 512]); } while (0)

  STAGE_AH(0, 0, 0);
  STAGE_B(0, 0);
  STAGE_AH(0, 1, 0);
  asm volatile("s_waitcnt vmcnt(2)" ::: "memory");
  __builtin_amdgcn_sched_barrier(0);
  __builtin_amdgcn_s_barrier();

  const int lrA = (wm * 64 + lo) * 64;
  const int lrB = (wn * (NB * 16) + lo) * 64;
  const int gk0 = ((hi) ^ swk) * 8;
  const int gk1 = ((4 + hi) ^ swk) * 8;

  bf16x8 af[4][2], blo[2][2], bhi[2];

  for (int kt = 0; kt < 16; ++kt) {
    const int c = kt & 1, nb = c ^ 1;
    const bool st = (kt < 15);
    const int koff = (kt + 1) * 64;
    const unsigned short* A0 = Alds[c][0];
    const unsigned short* A1 = Alds[c][1];
    const unsigned short* Bs = Blds[c];

    // ==== P1
#pragma unroll
    for (int ii = 0; ii < 4; ++ii) {
      af[ii][0] = *(const bf16x8*)&A0[lrA + ii * 1024 + gk0];
      af[ii][1] = *(const bf16x8*)&A0[lrA + ii * 1024 + gk1];
    }
#pragma unroll
    for (int jj = 0; jj < NB - 1; ++jj) {
      blo[jj][0] = *(const bf16x8*)&Bs[lrB + jj * 1024 + gk0];
      blo[jj][1] = *(const bf16x8*)&Bs[lrB + jj * 1024 + gk1];
    }
    if (st) STAGE_AH(nb, 0, koff);
    __builtin_amdgcn_s_barrier();
    asm volatile("s_waitcnt lgkmcnt(0)" ::: "memory");
    __builtin_amdgcn_sched_barrier(0);
    __builtin_amdgcn_s_setprio(1);
#pragma unroll
    for (int ii = 0; ii < 4; ++ii)
#pragma unroll
      for (int jj = 0; jj < NB - 1; ++jj) {
        acc[ii][jj] = MFMA16(af[ii][0], blo[jj][0], acc[ii][jj]);
        acc[ii][jj] = MFMA16(af[ii][1], blo[jj][1], acc[ii][jj]);
      }
    __builtin_amdgcn_s_setprio(0);
    __builtin_amdgcn_s_barrier();

    // ==== P2
    bhi[0] = *(const bf16x8*)&Bs[lrB + (NB - 1) * 1024 + gk0];
    bhi[1] = *(const bf16x8*)&Bs[lrB + (NB - 1) * 1024 + gk1];
    if (st) STAGE_B(nb, koff);
    __builtin_amdgcn_s_barrier();
    asm volatile("s_waitcnt lgkmcnt(0)" ::: "memory");
    __builtin_amdgcn_sched_barrier(0);
    __builtin_amdgcn_s_setprio(1);
#pragma unroll
    for (int ii = 0; ii < 4; ++ii) {
      acc[ii][NB - 1] = MFMA16(af[ii][0], bhi[0], acc[ii][NB - 1]);
      acc[ii][NB - 1] = MFMA16(af[ii][1], bhi[1], acc[ii][NB - 1]);
    }
    __builtin_amdgcn_s_setprio(0);
    if (st) {
      if constexpr (NB == 3) { asm volatile("s_waitcnt vmcnt(5)" ::: "memory"); }
      else                   { asm volatile("s_waitcnt vmcnt(4)" ::: "memory"); }
    } else {
      asm volatile("s_waitcnt vmcnt(0)" ::: "memory");
    }
    __builtin_amdgcn_sched_barrier(0);
    __builtin_amdgcn_s_barrier();

    // ==== P3
#pragma unroll
    for (int ii = 0; ii < 4; ++ii) {
      af[ii][0] = *(const bf16x8*)&A1[lrA + ii * 1024 + gk0];
      af[ii][1] = *(const bf16x8*)&A1[lrA + ii * 1024 + gk1];
    }
    if (st) STAGE_AH(nb, 1, koff);
    __builtin_amdgcn_s_barrier();
    asm volatile("s_waitcnt lgkmcnt(0)" ::: "memory");
    __builtin_amdgcn_sched_barrier(0);
    __builtin_amdgcn_s_setprio(1);
#pragma unroll
    for (int ii = 0; ii < 4; ++ii) {
      acc[4 + ii][NB - 1] = MFMA16(af[ii][0], bhi[0], acc[4 + ii][NB - 1]);
      acc[4 + ii][NB - 1] = MFMA16(af[ii][1], bhi[1], acc[4 + ii][NB - 1]);
    }
    __builtin_amdgcn_s_setprio(0);
    __builtin_amdgcn_s_barrier();

    // ==== P4
    __builtin_amdgcn_s_setprio(1);
#pragma unroll
    for (int ii = 0; ii < 4; ++ii)
#pragma unroll
      for (int jj = 0; jj < NB - 1; ++jj) {
        acc[4 + ii][jj] = MFMA16(af[ii][0], blo[jj][0], acc[4 + ii][jj]);
        acc[4 + ii][jj] = MFMA16(af[ii][1], blo[jj][1], acc[4 + ii][jj]);
      }
    __builtin_amdgcn_s_setprio(0);
    if (st) {
      asm volatile("s_waitcnt vmcnt(2)" ::: "memory");
      __builtin_amdgcn_sched_barrier(0);
    }
    __builtin_amdgcn_s_barrier();
  }
#undef STAGE_AH
#undef STAGE_B

  // ---- epilogue ----
  if (EPI == 0) {
    constexpr int SCW = 200;
    unsigned short* sc = (unsigned short*)&Alds[0][0][0];
#pragma unroll
    for (int i = 0; i < 8; ++i)
#pragma unroll
      for (int j = 0; j < NB; ++j)
#pragma unroll
        for (int r = 0; r < 4; ++r) {
          int rl = wm * 128 + i * 16 + hi * 4 + r;
          int cl = wn * (NB * 16) + j * 16 + lo;
          int colg = bn * BNT + cl;
          float v = acc[i][j][r] + bias[colg];
          // Q pre-scaled by 1/sqrt(64) * log2(e) (softmax runs in exp2 domain)
          if ((colg >> 10) == 0) v *= 0.1803368801111f;
          sc[rl * SCW + cl] = f2bf(v);
        }
    __syncthreads();
    for (int g = 0; g < NB * 4; ++g) {
      const int cbase = bn * BNT + g * 16;
      const int seg = cbase >> 10;
      const int cc = cbase & 1023;
      const int h = cc >> 6;
      if (seg < 2) {
        const int rl = t >> 1, hf = t & 1;
        bf16x8 vrow = *(const bf16x8*)&sc[rl * SCW + g * 16 + hf * 8];
        int rowg = bm * 256 + rl;
        int b = rowg >> 11, tt = rowg & 2047;
        int d = (cc & 63) + hf * 8;
        long bh = (long)(b * 16 + h);
        unsigned short* outp = (seg == 0 ? q_out : k_out);
        *(bf16x8*)&outp[(bh * 2048 + tt) * 64 + d] = vrow;
      } else {
        const int cl = g * 16 + (t & 15);
        const int r0 = (t >> 4) * 8;
        ushort8 pk;
#pragma unroll
        for (int k2 = 0; k2 < 8; ++k2) pk[k2] = sc[(r0 + k2) * SCW + cl];
        int rowg = bm * 256 + r0;
        int b = rowg >> 11, tt = rowg & 2047;
        int d = (cc & 63) + (t & 15);
        long bh = (long)(b * 16 + h);
        *(ushort8*)&vt_out[(bh * 64 + d) * 2048 + tt] = pk;
      }
    }
  } else {
#pragma unroll
    for (int i = 0; i < 8; ++i) {
#pragma unroll
      for (int j = 0; j < NB; ++j) {
#pragma unroll
        for (int r = 0; r < 4; ++r) {
          int row = bm * 256 + wm * 128 + i * 16 + hi * 4 + r;
          int col = bn * BNT + wn * (NB * 16) + j * 16 + lo;
          float v = acc[i][j][r] + bias[col];
          f_out[(long)row * N + col] = v;
        }
      }
    }
  }
}

// ------- causal flash attention v11: 32x32 swapped QK^T, in-register P -------
// m214-style port: per wave 32 q-rows. QK^T via mfma_32x32x16(K, Q): lane
// holds S[k][q=l&31], k_local = (r&3)+8*(r>>2)+4*(l>>5) (verified C/D layout).
// Softmax max-free (exp2 domain). P -> bf16 IN REGISTER: 8 cvt_pk + 4
// permlane32_swap per 32-k subtile produce the PV B-frags directly — no P
// LDS round-trip (removes 4 ds_write + lgkmcnt(0) + 2 ds_read serial bubble
// per step and the 16 KB pbuf). PV: O^T[d][q] = mfma_32x32x16(Vt_frag, P).
// Rowsum on VALU (tree) with ONE shfl_xor(32) partner merge per strip.
// K/V LDS reads per q-row halved (32 rows share frags). 256 thr / 4 waves,
// 128-row strips, grid 64x16 longest-first (v10 dispatch), LDS 50.4 KB ->
// 3 blocks/CU = 12 waves x 32 rows = 384 rows in flight.
__global__ __launch_bounds__(256, 4)
void attn_kernel(const unsigned short* __restrict__ Q,
                 const unsigned short* __restrict__ K,
                 const unsigned short* __restrict__ Vt,
                 unsigned short* __restrict__ Y) {
  alignas(16) __shared__ unsigned short Kbuf[2][64 * 64];
  alignas(16) __shared__ unsigned short Vbuf[2][64 * 64];
  alignas(16) __shared__ unsigned short obuf[4][32 * 72];
  const int t = threadIdx.x, w = t >> 6, l = t & 63;
  const int q5 = l & 31, hi5 = l >> 5, sw = l & 7;
  const int bh = blockIdx.x;
  const int s = 15 - blockIdx.y;       // longest strip first
  const int b = bh >> 4, h = bh & 15;
  const int nTot = 2 * s + 2;
  const unsigned short* Qp = Q + (long)bh * 2048 * 64;
  const unsigned short* Kp = K + (long)bh * 2048 * 64;
  const unsigned short* Vp = Vt + (long)bh * 64 * 2048;

  const int qbw = s * 128 + w * 32;

  // Q B-frags: qf[m] = Q[qbw + q5][m*16 + hi5*8 + j]  (B[d][col=q])
  bf16x8 qf[4];
#pragma unroll
  for (int m = 0; m < 4; ++m)
    qf[m] = *(const bf16x8*)&Qp[(qbw + q5) * 64 + m * 16 + hi5 * 8];

  f32x16 oacc[2];
#pragma unroll
  for (int dh = 0; dh < 2; ++dh)
#pragma unroll
    for (int r = 0; r < 16; ++r) oacc[dh][r] = 0.f;
  float lsum = 0.f;

  // staging: lane l of wave w -> LDS row w*8 + (l>>3) (and +32), granule l&7;
  // source granule inverse-swizzled by row&7 == l>>3.
  const int rowk = w * 8 + (l >> 3);
  const int scw = ((l & 7) ^ (l >> 3)) * 8;

#define STAGE(kvoff, bufidx)                                              \
  do {                                                                    \
    unsigned short* KB_ = Kbuf[bufidx] + w * 512;                         \
    unsigned short* VB_ = Vbuf[bufidx] + w * 512;                         \
    gload16(Kp + (long)((kvoff) + rowk) * 64 + scw, KB_);                 \
    gload16(Kp + (long)((kvoff) + 32 + rowk) * 64 + scw, KB_ + 2048);     \
    gload16(Vp + (long)rowk * 2048 + (kvoff) + scw, VB_);                 \
    gload16(Vp + (long)(32 + rowk) * 2048 + (kvoff) + scw, VB_ + 2048);   \
  } while (0)

  STAGE(0, 0);
  __syncthreads();

  for (int g = 0; g < nTot; ++g) {
    const int kvb = g * 64;
    const int cur = g & 1;
    if (g + 1 < nTot) STAGE((g + 1) * 64, cur ^ 1);
    if (kvb <= qbw + 31) {
      const unsigned short* KB = Kbuf[cur];
      const unsigned short* VB = Vbuf[cur];
#pragma unroll
      for (int kt = 0; kt < 2; ++kt) {
        if (kvb + kt * 32 <= qbw + 31) {
          // ---- QK^T: S[k][q], 4 MFMA over d-slices ----
          f32x16 sacc;
#pragma unroll
          for (int r = 0; r < 16; ++r) sacc[r] = 0.f;
          __builtin_amdgcn_s_setprio(1);
#pragma unroll
          for (int m = 0; m < 4; ++m) {
            bf16x8 kf = *(const bf16x8*)&KB[(kt * 32 + q5) * 64 + ((2 * m + hi5) ^ sw) * 8];
            sacc = MFMA32(kf, qf[m], sacc);
          }
          __builtin_amdgcn_s_setprio(0);
          // ---- causal mask: k = kvb + kt*32 + (r&3)+8*(r>>2)+4*hi5 > q ----
          if (kvb + kt * 32 + 31 > qbw) {
            const int lim = qbw + q5 - kvb - kt * 32 - 4 * hi5;
#pragma unroll
            for (int r = 0; r < 16; ++r)
              if (((r & 3) + 8 * (r >> 2)) > lim) sacc[r] = -__builtin_inff();
          }
          // ---- max-free softmax numerators + local rowsum ----
          float p[16];
#pragma unroll
          for (int r = 0; r < 16; ++r) p[r] = exp2f(sacc[r]);
          {
            float t0 = (p[0] + p[1]) + (p[2] + p[3]);
            float t1 = (p[4] + p[5]) + (p[6] + p[7]);
            float t2 = (p[8] + p[9]) + (p[10] + p[11]);
            float t3 = (p[12] + p[13]) + (p[14] + p[15]);
            lsum += (t0 + t1) + (t2 + t3);
          }
          // ---- in-register P -> bf16 B-frags (cvt_pk + permlane32_swap) ----
          unsigned int u0, u1, u2, u3, u4, u5, u6, u7;
          asm("v_cvt_pk_bf16_f32 %0, %1, %2" : "=v"(u0) : "v"(p[0]), "v"(p[1]));
          asm("v_cvt_pk_bf16_f32 %0, %1, %2" : "=v"(u1) : "v"(p[2]), "v"(p[3]));
          asm("v_cvt_pk_bf16_f32 %0, %1, %2" : "=v"(u2) : "v"(p[4]), "v"(p[5]));
          asm("v_cvt_pk_bf16_f32 %0, %1, %2" : "=v"(u3) : "v"(p[6]), "v"(p[7]));
          asm("v_cvt_pk_bf16_f32 %0, %1, %2" : "=v"(u4) : "v"(p[8]), "v"(p[9]));
          asm("v_cvt_pk_bf16_f32 %0, %1, %2" : "=v"(u5) : "v"(p[10]), "v"(p[11]));
          asm("v_cvt_pk_bf16_f32 %0, %1, %2" : "=v"(u6) : "v"(p[12]), "v"(p[13]));
          asm("v_cvt_pk_bf16_f32 %0, %1, %2" : "=v"(u7) : "v"(p[14]), "v"(p[15]));
          asm volatile("v_permlane32_swap_b32 %0, %1" : "+v"(u0), "+v"(u2));
          asm volatile("v_permlane32_swap_b32 %0, %1" : "+v"(u1), "+v"(u3));
          asm volatile("v_permlane32_swap_b32 %0, %1" : "+v"(u4), "+v"(u6));
          asm volatile("v_permlane32_swap_b32 %0, %1" : "+v"(u5), "+v"(u7));
          u32x4 w0 = {u0, u1, u2, u3};
          u32x4 w1 = {u4, u5, u6, u7};
          bf16x8 pf0 = __builtin_bit_cast(bf16x8, w0);   // k' = 16*0 + (l>>5)*8 + j
          bf16x8 pf1 = __builtin_bit_cast(bf16x8, w1);   // k' = 16*1 + ...
          // ---- PV: O^T[d][q] += Vt_frag x P ----
          __builtin_amdgcn_s_setprio(1);
#pragma unroll
          for (int dh = 0; dh < 2; ++dh) {
            bf16x8 v0 = *(const bf16x8*)&VB[(dh * 32 + q5) * 64 + ((kt * 4 + 0 + hi5) ^ sw) * 8];
            bf16x8 v1 = *(const bf16x8*)&VB[(dh * 32 + q5) * 64 + ((kt * 4 + 2 + hi5) ^ sw) * 8];
            oacc[dh] = MFMA32(v0, pf0, oacc[dh]);
            oacc[dh] = MFMA32(v1, pf1, oacc[dh]);
          }
          __builtin_amdgcn_s_setprio(0);
        }
      }
    }
    __syncthreads();
  }

  // ---- epilogue: merge partner rowsum, scale, LDS bounce, coalesced Y ----
  lsum += __shfl_xor(lsum, 32);
  float inv = 1.0f / lsum;
  unsigned short* ow = obuf[w];
#pragma unroll
  for (int dh = 0; dh < 2; ++dh)
#pragma unroll
    for (int r = 0; r < 16; ++r) {
      int d = dh * 32 + (r & 3) + 8 * (r >> 2) + 4 * hi5;
      ow[q5 * 72 + d] = f2bf(oacc[dh][r] * inv);
    }
  // per-wave private slice: no cross-wave barrier needed
  const int orow = l >> 1, och = l & 1;
  long ybase = ((long)b * 2048 + qbw + orow) * 1024 + h * 64 + och * 32;
#pragma unroll
  for (int c = 0; c < 4; ++c) {
    bf16x8 v = *(const bf16x8*)&ow[orow * 72 + och * 32 + c * 8];
    *(bf16x8*)&Y[ybase + c * 8] = v;
  }
#undef STAGE
}

extern "C" void kernel_launch(void* const* d_in, const int* in_sizes, int n_in,
                              void* d_out, int out_size, void* d_ws, size_t ws_size,
                              hipStream_t stream) {
  const float* x      = (const float*)d_in[0];
  const float* w_attn = (const float*)d_in[1];
  const float* b_attn = (const float*)d_in[2];
  const float* w_proj = (const float*)d_in[3];
  const float* b_proj = (const float*)d_in[4];
  float* out = (float*)d_out;

  const long NX = 8192L * 1024;
  const long NWA = 3072L * 1024;
  const long NWP = 1024L * 1024;
  const long NQ = 64L * 2048 * 64;

  char* ws = (char*)d_ws;
  unsigned short* xb  = (unsigned short*)ws; ws += NX * 2;
  unsigned short* wab = (unsigned short*)ws; ws += NWA * 2;
  unsigned short* wpb = (unsigned short*)ws; ws += NWP * 2;
  unsigned short* qb  = (unsigned short*)ws; ws += NQ * 2;
  unsigned short* kb  = (unsigned short*)ws; ws += NQ * 2;
  unsigned short* vtb = (unsigned short*)ws; ws += NQ * 2;
  unsigned short* yb  = (unsigned short*)ws; ws += NX * 2;

  cvt_all<<<2048, 256, 0, stream>>>(x, w_attn, w_proj, xb, wab, wpb);

  dim3 g1(32, 16);   // 512 blocks = 2 exact rounds @ 1 block/CU
  gemm_bt<0, 3><<<g1, 512, 0, stream>>>(xb, wab, b_attn, 8192, 3072, 1024,
                                        qb, kb, vtb, nullptr);
  dim3 ga(64, 16);   // 1024 strip-blocks, longest-first, 3 blocks/CU resident
  attn_kernel<<<ga, 256, 0, stream>>>(qb, kb, vtb, yb);
  dim3 g2(32, 8);    // 256 blocks = 1 exact round
  gemm_bt<1, 2><<<g2, 512, 0, stream>>>(yb, wpb, b_proj, 8192, 1024, 1024,
                                        nullptr, nullptr, nullptr, out);
}

// Round 15
// 159.802 us; speedup vs baseline: 1.0630x; 1.0630x over previous
//
#include <hip/hip_runtime.h>
#include <hip/hip_bf16.h>
#include <stdint.h>

typedef __attribute__((ext_vector_type(8))) short bf16x8;
typedef __attribute__((ext_vector_type(8))) unsigned short ushort8;
typedef __attribute__((ext_vector_type(4))) float f32x4;

#define MFMA16(a, b, c) __builtin_amdgcn_mfma_f32_16x16x32_bf16((a), (b), (c), 0, 0, 0)

__device__ __forceinline__ unsigned short f2bf(float f) {
  unsigned int u = __builtin_bit_cast(unsigned int, f);
  unsigned int r = (u + 0x7fffu + ((u >> 16) & 1u)) >> 16;
  return (unsigned short)r;
}

__device__ __forceinline__ void gload16(const unsigned short* g, unsigned short* lds_dst) {
  __builtin_amdgcn_global_load_lds(
      (const __attribute__((address_space(1))) unsigned int*)g,
      (__attribute__((address_space(3))) unsigned int*)lds_dst, 16, 0, 0);
}

// ---------------- fused f32 -> bf16 conversion (single launch) ----------------
__global__ void cvt_all(const float* __restrict__ x, const float* __restrict__ wa,
                        const float* __restrict__ wp, unsigned short* __restrict__ xb,
                        unsigned short* __restrict__ wab, unsigned short* __restrict__ wpb) {
  const int C0 = 1048576;
  const int C1 = 1441792;
  const int C2 = 1572864;
  int i = blockIdx.x * blockDim.x + threadIdx.x;
  const int stride = gridDim.x * blockDim.x;
  for (; i < C2; i += stride) {
    const float* src; unsigned short* dst; long e;
    if (i < C0)      { src = x;  dst = xb;  e = (long)i * 8; }
    else if (i < C1) { src = wa; dst = wab; e = (long)(i - C0) * 8; }
    else             { src = wp; dst = wpb; e = (long)(i - C1) * 8; }
    float4 v0 = *(const float4*)(src + e);
    float4 v1 = *(const float4*)(src + e + 4);
    ushort8 o;
    o[0] = f2bf(v0.x); o[1] = f2bf(v0.y); o[2] = f2bf(v0.z); o[3] = f2bf(v0.w);
    o[4] = f2bf(v1.x); o[5] = f2bf(v1.y); o[6] = f2bf(v1.z); o[7] = f2bf(v1.w);
    *(ushort8*)(dst + e) = o;
  }
}

// ------- 256 x (NB*64) B^T GEMM: r6 schedule + LDS-transpose epilogue -------
// K-loop: best measured (r6). Epilogue (EPI==0): f2bf tile -> LDS (stride
// 200, 16B-aligned rows, reusing dead staging buffers), then per 16-col
// group either b128 row-reads (q/k) or u16 column-reads (vt) + fully-
// coalesced 16B global stores (removes the 4 KB-stride 2B V^T scatter).
template <int EPI, int NB>
__global__ __launch_bounds__(512, 2)
void gemm_bt(const unsigned short* __restrict__ A,
             const unsigned short* __restrict__ Bt,
             const float* __restrict__ bias,
             int M, int N, int K,
             unsigned short* __restrict__ q_out,
             unsigned short* __restrict__ k_out,
             unsigned short* __restrict__ vt_out,
             float* __restrict__ f_out) {
  constexpr int BNT = NB * 64;
  alignas(16) __shared__ unsigned short Alds[2][2][128 * 64];
  alignas(16) __shared__ unsigned short Blds[2][BNT * 64];
  const int t = threadIdx.x, w = t >> 6, l = t & 63;
  const int bm = blockIdx.x, bn = blockIdx.y;
  const int wm = w >> 2, wn = w & 3;
  const int lo = l & 15, hi = l >> 4, swk = lo & 7;

  f32x4 acc[8][NB];
  const f32x4 zero = {0.f, 0.f, 0.f, 0.f};
#pragma unroll
  for (int i = 0; i < 8; ++i)
#pragma unroll
    for (int j = 0; j < NB; ++j) acc[i][j] = zero;

  const int sr = t >> 3;
  const int gsrcE = ((t & 7) ^ (sr & 7)) * 8;
  const unsigned short* Asrc = A + (long)(bm * 256 + sr) * K + gsrcE;
  const unsigned short* Bsrc = Bt + (long)(bn * BNT + sr) * K + gsrcE;

#define STAGE_AH(sb, qh, koff) do {                                    \
    unsigned short* d_ = &Alds[sb][qh][w * 512];                       \
    const unsigned short* s_ = Asrc + (long)(qh) * 64 * K + (koff);    \
    gload16(s_, d_); gload16(s_ + 128L * K, d_ + 4096); } while (0)
#define STAGE_B(sb, koff) do {                                         \
    _Pragma("unroll")                                                  \
    for (int c_ = 0; c_ < NB; ++c_)                                    \
      gload16(Bsrc + (long)c_ * 64 * K + (koff),                       \
              &Blds[sb][c_ * 4096 + w * 512]); } while (0)

  STAGE_AH(0, 0, 0);
  STAGE_B(0, 0);
  STAGE_AH(0, 1, 0);
  asm volatile("s_waitcnt vmcnt(2)" ::: "memory");
  __builtin_amdgcn_sched_barrier(0);
  __builtin_amdgcn_s_barrier();

  const int lrA = (wm * 64 + lo) * 64;
  const int lrB = (wn * (NB * 16) + lo) * 64;
  const int gk0 = ((hi) ^ swk) * 8;
  const int gk1 = ((4 + hi) ^ swk) * 8;

  bf16x8 af[4][2], blo[2][2], bhi[2];

  for (int kt = 0; kt < 16; ++kt) {
    const int c = kt & 1, nb = c ^ 1;
    const bool st = (kt < 15);
    const int koff = (kt + 1) * 64;
    const unsigned short* A0 = Alds[c][0];
    const unsigned short* A1 = Alds[c][1];
    const unsigned short* Bs = Blds[c];

    // ==== P1
#pragma unroll
    for (int ii = 0; ii < 4; ++ii) {
      af[ii][0] = *(const bf16x8*)&A0[lrA + ii * 1024 + gk0];
      af[ii][1] = *(const bf16x8*)&A0[lrA + ii * 1024 + gk1];
    }
#pragma unroll
    for (int jj = 0; jj < NB - 1; ++jj) {
      blo[jj][0] = *(const bf16x8*)&Bs[lrB + jj * 1024 + gk0];
      blo[jj][1] = *(const bf16x8*)&Bs[lrB + jj * 1024 + gk1];
    }
    if (st) STAGE_AH(nb, 0, koff);
    __builtin_amdgcn_s_barrier();
    asm volatile("s_waitcnt lgkmcnt(0)" ::: "memory");
    __builtin_amdgcn_sched_barrier(0);
    __builtin_amdgcn_s_setprio(1);
#pragma unroll
    for (int ii = 0; ii < 4; ++ii)
#pragma unroll
      for (int jj = 0; jj < NB - 1; ++jj) {
        acc[ii][jj] = MFMA16(af[ii][0], blo[jj][0], acc[ii][jj]);
        acc[ii][jj] = MFMA16(af[ii][1], blo[jj][1], acc[ii][jj]);
      }
    __builtin_amdgcn_s_setprio(0);
    __builtin_amdgcn_s_barrier();

    // ==== P2
    bhi[0] = *(const bf16x8*)&Bs[lrB + (NB - 1) * 1024 + gk0];
    bhi[1] = *(const bf16x8*)&Bs[lrB + (NB - 1) * 1024 + gk1];
    if (st) STAGE_B(nb, koff);
    __builtin_amdgcn_s_barrier();
    asm volatile("s_waitcnt lgkmcnt(0)" ::: "memory");
    __builtin_amdgcn_sched_barrier(0);
    __builtin_amdgcn_s_setprio(1);
#pragma unroll
    for (int ii = 0; ii < 4; ++ii) {
      acc[ii][NB - 1] = MFMA16(af[ii][0], bhi[0], acc[ii][NB - 1]);
      acc[ii][NB - 1] = MFMA16(af[ii][1], bhi[1], acc[ii][NB - 1]);
    }
    __builtin_amdgcn_s_setprio(0);
    if (st) {
      if constexpr (NB == 3) { asm volatile("s_waitcnt vmcnt(5)" ::: "memory"); }
      else                   { asm volatile("s_waitcnt vmcnt(4)" ::: "memory"); }
    } else {
      asm volatile("s_waitcnt vmcnt(0)" ::: "memory");
    }
    __builtin_amdgcn_sched_barrier(0);
    __builtin_amdgcn_s_barrier();

    // ==== P3
#pragma unroll
    for (int ii = 0; ii < 4; ++ii) {
      af[ii][0] = *(const bf16x8*)&A1[lrA + ii * 1024 + gk0];
      af[ii][1] = *(const bf16x8*)&A1[lrA + ii * 1024 + gk1];
    }
    if (st) STAGE_AH(nb, 1, koff);
    __builtin_amdgcn_s_barrier();
    asm volatile("s_waitcnt lgkmcnt(0)" ::: "memory");
    __builtin_amdgcn_sched_barrier(0);
    __builtin_amdgcn_s_setprio(1);
#pragma unroll
    for (int ii = 0; ii < 4; ++ii) {
      acc[4 + ii][NB - 1] = MFMA16(af[ii][0], bhi[0], acc[4 + ii][NB - 1]);
      acc[4 + ii][NB - 1] = MFMA16(af[ii][1], bhi[1], acc[4 + ii][NB - 1]);
    }
    __builtin_amdgcn_s_setprio(0);
    __builtin_amdgcn_s_barrier();

    // ==== P4
    __builtin_amdgcn_s_setprio(1);
#pragma unroll
    for (int ii = 0; ii < 4; ++ii)
#pragma unroll
      for (int jj = 0; jj < NB - 1; ++jj) {
        acc[4 + ii][jj] = MFMA16(af[ii][0], blo[jj][0], acc[4 + ii][jj]);
        acc[4 + ii][jj] = MFMA16(af[ii][1], blo[jj][1], acc[4 + ii][jj]);
      }
    __builtin_amdgcn_s_setprio(0);
    if (st) {
      asm volatile("s_waitcnt vmcnt(2)" ::: "memory");
      __builtin_amdgcn_sched_barrier(0);
    }
    __builtin_amdgcn_s_barrier();
  }
#undef STAGE_AH
#undef STAGE_B

  // ---- epilogue ----
  if (EPI == 0) {
    constexpr int SCW = 200;
    unsigned short* sc = (unsigned short*)&Alds[0][0][0];
#pragma unroll
    for (int i = 0; i < 8; ++i)
#pragma unroll
      for (int j = 0; j < NB; ++j)
#pragma unroll
        for (int r = 0; r < 4; ++r) {
          int rl = wm * 128 + i * 16 + hi * 4 + r;
          int cl = wn * (NB * 16) + j * 16 + lo;
          int colg = bn * BNT + cl;
          float v = acc[i][j][r] + bias[colg];
          // Q pre-scaled by 1/sqrt(64) * log2(e) (softmax runs in exp2 domain)
          if ((colg >> 10) == 0) v *= 0.1803368801111f;
          sc[rl * SCW + cl] = f2bf(v);
        }
    __syncthreads();
    for (int g = 0; g < NB * 4; ++g) {
      const int cbase = bn * BNT + g * 16;
      const int seg = cbase >> 10;
      const int cc = cbase & 1023;
      const int h = cc >> 6;
      if (seg < 2) {
        const int rl = t >> 1, hf = t & 1;
        bf16x8 vrow = *(const bf16x8*)&sc[rl * SCW + g * 16 + hf * 8];
        int rowg = bm * 256 + rl;
        int b = rowg >> 11, tt = rowg & 2047;
        int d = (cc & 63) + hf * 8;
        long bh = (long)(b * 16 + h);
        unsigned short* outp = (seg == 0 ? q_out : k_out);
        *(bf16x8*)&outp[(bh * 2048 + tt) * 64 + d] = vrow;
      } else {
        const int cl = g * 16 + (t & 15);
        const int r0 = (t >> 4) * 8;
        ushort8 pk;
#pragma unroll
        for (int k2 = 0; k2 < 8; ++k2) pk[k2] = sc[(r0 + k2) * SCW + cl];
        int rowg = bm * 256 + r0;
        int b = rowg >> 11, tt = rowg & 2047;
        int d = (cc & 63) + (t & 15);
        long bh = (long)(b * 16 + h);
        *(ushort8*)&vt_out[(bh * 64 + d) * 2048 + tt] = pk;
      }
    }
  } else {
#pragma unroll
    for (int i = 0; i < 8; ++i) {
#pragma unroll
      for (int j = 0; j < NB; ++j) {
#pragma unroll
        for (int r = 0; r < 4; ++r) {
          int row = bm * 256 + wm * 128 + i * 16 + hi * 4 + r;
          int col = bn * BNT + wn * (NB * 16) + j * 16 + lo;
          float v = acc[i][j][r] + bias[col];
          f_out[(long)row * N + col] = v;
        }
      }
    }
  }
}

// ---------------- causal flash attention v10 (best measured) ----------------
// One 128-row strip per block (strip s: 2s+2 KV steps), grid 64 x 16 = 1024
// blocks, longest strips dispatched first; launch_bounds(512,6) -> 3 blocks/CU.
// Max-free softmax (exp2 domain). v11's 32x32 in-register-P rewrite regressed
// (occupancy 54 -> 27%, bank conflicts 2.2M -> 4.5M): this kernel's operating
// point is occupancy-dominated — keep the 8-wave 16-row structure.
__global__ __launch_bounds__(512, 6)
void attn_kernel(const unsigned short* __restrict__ Q,
                 const unsigned short* __restrict__ K,
                 const unsigned short* __restrict__ Vt,
                 unsigned short* __restrict__ Y) {
  alignas(16) __shared__ unsigned short Kbuf[2][64 * 64];
  alignas(16) __shared__ unsigned short Vbuf[2][64 * 64];
  alignas(16) __shared__ unsigned short pbuf[8][16 * 64];
  const int t = threadIdx.x, w = t >> 6, l = t & 63;
  const int lo = l & 15, hi = l >> 4;
  const int bh = blockIdx.x;
  const int s = 15 - blockIdx.y;       // longest strip (s=15, 32 steps) first
  const int b = bh >> 4, h = bh & 15;
  const int nTot = 2 * s + 2;
  const unsigned short* Qp = Q + (long)bh * 2048 * 64;
  const unsigned short* Kp = K + (long)bh * 2048 * 64;
  const unsigned short* Vp = Vt + (long)bh * 64 * 2048;
  unsigned short* pw = pbuf[w];

  const short one_bf = (short)0x3F80;
  const bf16x8 ones = {one_bf, one_bf, one_bf, one_bf, one_bf, one_bf, one_bf, one_bf};
  const f32x4 zero = {0.f, 0.f, 0.f, 0.f};

  const int qb = s * 128 + w * 16;

  bf16x8 qf0, qf1;
  f32x4 lsum;
  f32x4 oacc[4];

  qf0 = *(const bf16x8*)&Qp[(qb + lo) * 64 + hi * 8];
  qf1 = *(const bf16x8*)&Qp[(qb + lo) * 64 + 32 + hi * 8];
  lsum = zero;
#pragma unroll
  for (int dg = 0; dg < 4; ++dg) oacc[dg] = zero;

  const int srow = t >> 3;
  const int scw = ((t & 7) ^ (srow & 7)) * 8;
  const int sw = lo & 7;

#define STAGE(kvoff, bufidx)                                          \
  do {                                                                \
    unsigned short* KB_ = Kbuf[bufidx] + w * 512;                     \
    unsigned short* VB_ = Vbuf[bufidx] + w * 512;                     \
    gload16(Kp + (long)((kvoff) + srow) * 64 + scw, KB_);             \
    gload16(Vp + (long)srow * 2048 + (kvoff) + scw, VB_);             \
  } while (0)

  STAGE(0, 0);
  __syncthreads();

  for (int g = 0; g < nTot; ++g) {
    const int kvb = g * 64;
    const int cur = g & 1;
    if (g + 1 < nTot) {
      STAGE((g + 1) * 64, cur ^ 1);
    }
    if (kvb <= qb + 15) {
      const unsigned short* KB = Kbuf[cur];
      const unsigned short* VB = Vbuf[cur];
      f32x4 sc[4];
#pragma unroll
      for (int cg = 0; cg < 4; ++cg) sc[cg] = zero;
      __builtin_amdgcn_s_setprio(1);
#pragma unroll
      for (int cg = 0; cg < 4; ++cg) {
        bf16x8 k0 = *(const bf16x8*)&KB[(cg * 16 + lo) * 64 + ((hi) ^ sw) * 8];
        bf16x8 k1 = *(const bf16x8*)&KB[(cg * 16 + lo) * 64 + ((4 + hi) ^ sw) * 8];
        sc[cg] = MFMA16(k0, qf0, sc[cg]);
        sc[cg] = MFMA16(k1, qf1, sc[cg]);
      }
      __builtin_amdgcn_s_setprio(0);
      if (kvb + 63 > qb) {
        const int limit = qb + lo - kvb;
#pragma unroll
        for (int cg = 0; cg < 4; ++cg)
#pragma unroll
          for (int r = 0; r < 4; ++r)
            if (cg * 16 + hi * 4 + r > limit) sc[cg][r] = -__builtin_inff();
      }
      // max-free softmax numerator: p = exp2(s)
#pragma unroll
      for (int cg = 0; cg < 4; ++cg) {
        float p0 = exp2f(sc[cg][0]);
        float p1 = exp2f(sc[cg][1]);
        float p2 = exp2f(sc[cg][2]);
        float p3 = exp2f(sc[cg][3]);
        unsigned int u0, u1;
        asm("v_cvt_pk_bf16_f32 %0, %1, %2" : "=v"(u0) : "v"(p0), "v"(p1));
        asm("v_cvt_pk_bf16_f32 %0, %1, %2" : "=v"(u1) : "v"(p2), "v"(p3));
        const int gg = (cg * 2 + (hi >> 1)) ^ sw;
        uint2 val; val.x = u0; val.y = u1;
        *(uint2*)&pw[lo * 64 + gg * 8 + (hi & 1) * 4] = val;
      }
      asm volatile("s_waitcnt lgkmcnt(0)" ::: "memory");
      bf16x8 pa0 = *(const bf16x8*)&pw[lo * 64 + ((hi) ^ sw) * 8];
      bf16x8 pa1 = *(const bf16x8*)&pw[lo * 64 + ((4 + hi) ^ sw) * 8];
      __builtin_amdgcn_s_setprio(1);
      lsum = MFMA16(pa0, ones, lsum);
      lsum = MFMA16(pa1, ones, lsum);
#pragma unroll
      for (int dg = 0; dg < 4; ++dg) {
        bf16x8 vv0 = *(const bf16x8*)&VB[(dg * 16 + lo) * 64 + ((hi) ^ sw) * 8];
        bf16x8 vv1 = *(const bf16x8*)&VB[(dg * 16 + lo) * 64 + ((4 + hi) ^ sw) * 8];
        oacc[dg] = MFMA16(pa0, vv0, oacc[dg]);
        oacc[dg] = MFMA16(pa1, vv1, oacc[dg]);
      }
      __builtin_amdgcn_s_setprio(0);
    }
    __syncthreads();
  }

  // ---- epilogue ----
#pragma unroll
  for (int r = 0; r < 4; ++r) {
    float inv = 1.0f / lsum[r];
    int rowg = qb + hi * 4 + r;
    long base = ((long)b * 2048 + rowg) * 1024 + h * 64;
#pragma unroll
    for (int dg = 0; dg < 4; ++dg)
      Y[base + dg * 16 + lo] = f2bf(oacc[dg][r] * inv);
  }
#undef STAGE
}

extern "C" void kernel_launch(void* const* d_in, const int* in_sizes, int n_in,
                              void* d_out, int out_size, void* d_ws, size_t ws_size,
                              hipStream_t stream) {
  const float* x      = (const float*)d_in[0];
  const float* w_attn = (const float*)d_in[1];
  const float* b_attn = (const float*)d_in[2];
  const float* w_proj = (const float*)d_in[3];
  const float* b_proj = (const float*)d_in[4];
  float* out = (float*)d_out;

  const long NX = 8192L * 1024;
  const long NWA = 3072L * 1024;
  const long NWP = 1024L * 1024;
  const long NQ = 64L * 2048 * 64;

  char* ws = (char*)d_ws;
  unsigned short* xb  = (unsigned short*)ws; ws += NX * 2;
  unsigned short* wab = (unsigned short*)ws; ws += NWA * 2;
  unsigned short* wpb = (unsigned short*)ws; ws += NWP * 2;
  unsigned short* qb  = (unsigned short*)ws; ws += NQ * 2;
  unsigned short* kb  = (unsigned short*)ws; ws += NQ * 2;
  unsigned short* vtb = (unsigned short*)ws; ws += NQ * 2;
  unsigned short* yb  = (unsigned short*)ws; ws += NX * 2;

  cvt_all<<<2048, 256, 0, stream>>>(x, w_attn, w_proj, xb, wab, wpb);

  dim3 g1(32, 16);   // 512 blocks = 2 exact rounds @ 1 block/CU
  gemm_bt<0, 3><<<g1, 512, 0, stream>>>(xb, wab, b_attn, 8192, 3072, 1024,
                                        qb, kb, vtb, nullptr);
  dim3 ga(64, 16);   // 1024 strip-blocks, longest-first, 3 blocks/CU resident
  attn_kernel<<<ga, 512, 0, stream>>>(qb, kb, vtb, yb);
  dim3 g2(32, 8);    // 256 blocks = 1 exact round
  gemm_bt<1, 2><<<g2, 512, 0, stream>>>(yb, wpb, b_proj, 8192, 1024, 1024,
                                        nullptr, nullptr, nullptr, out);
}